// Round 1
// baseline (649.314 us; speedup 1.0000x reference)
//
#include <hip/hip_runtime.h>
#include <math.h>

// Problem constants (from reference): B=8, OUT_LEN=1024, IN_LEN=4096, H=256
#define B_    8
#define OLEN  1024
#define ILEN  4096
#define HDIM  256
#define TS    64   // output tile (TS x TS)
#define KC    64   // K-chunk
#define PAD   4    // LDS leading-dim pad (keeps float4 alignment, breaks pow2 stride)

// ---------------------------------------------------------------------------
// K1: scores S[b][o][i] = sum_h Q[b][o][h] * E[b][i][h]   (K = HDIM = 256)
// Writes raw scores into the attn region of d_out; masking happens in softmax.
// ---------------------------------------------------------------------------
__global__ __launch_bounds__(256) void k_scores(const float* __restrict__ Q,
                                                const float* __restrict__ E,
                                                float* __restrict__ S) {
  const int b = blockIdx.z, ot = blockIdx.y, it = blockIdx.x;
  const float* Qb = Q + ((size_t)b * OLEN + (size_t)ot * TS) * HDIM;
  const float* Eb = E + ((size_t)b * ILEN + (size_t)it * TS) * HDIM;
  float* Sb = S + ((size_t)b * OLEN + (size_t)ot * TS) * ILEN + (size_t)it * TS;

  __shared__ __align__(16) float At[KC][TS + PAD];  // Q chunk, transposed: At[k][o]
  __shared__ __align__(16) float Bt[KC][TS + PAD];  // E chunk, transposed: Bt[k][i]

  const int t  = threadIdx.x;
  const int tx = t & 15, ty = t >> 4;   // micro-tile: rows 4*ty.., cols 4*tx..
  const int lr = t >> 2;                // load row 0..63
  const int lf = (t & 3) * 4;           // load float4 col base

  float acc[4][4] = {{0.f, 0.f, 0.f, 0.f}};

  for (int kc = 0; kc < HDIM; kc += KC) {
#pragma unroll
    for (int q = 0; q < 4; ++q) {
      const int k0 = lf + 16 * q;  // 0..60 step 4
      float4 v = *(const float4*)&Qb[(size_t)lr * HDIM + kc + k0];
      At[k0 + 0][lr] = v.x; At[k0 + 1][lr] = v.y;
      At[k0 + 2][lr] = v.z; At[k0 + 3][lr] = v.w;
      float4 w = *(const float4*)&Eb[(size_t)lr * HDIM + kc + k0];
      Bt[k0 + 0][lr] = w.x; Bt[k0 + 1][lr] = w.y;
      Bt[k0 + 2][lr] = w.z; Bt[k0 + 3][lr] = w.w;
    }
    __syncthreads();
#pragma unroll
    for (int kk = 0; kk < KC; ++kk) {
      float4 a  = *(const float4*)&At[kk][4 * ty];
      float4 bb = *(const float4*)&Bt[kk][4 * tx];
      acc[0][0] = fmaf(a.x, bb.x, acc[0][0]); acc[0][1] = fmaf(a.x, bb.y, acc[0][1]);
      acc[0][2] = fmaf(a.x, bb.z, acc[0][2]); acc[0][3] = fmaf(a.x, bb.w, acc[0][3]);
      acc[1][0] = fmaf(a.y, bb.x, acc[1][0]); acc[1][1] = fmaf(a.y, bb.y, acc[1][1]);
      acc[1][2] = fmaf(a.y, bb.z, acc[1][2]); acc[1][3] = fmaf(a.y, bb.w, acc[1][3]);
      acc[2][0] = fmaf(a.z, bb.x, acc[2][0]); acc[2][1] = fmaf(a.z, bb.y, acc[2][1]);
      acc[2][2] = fmaf(a.z, bb.z, acc[2][2]); acc[2][3] = fmaf(a.z, bb.w, acc[2][3]);
      acc[3][0] = fmaf(a.w, bb.x, acc[3][0]); acc[3][1] = fmaf(a.w, bb.y, acc[3][1]);
      acc[3][2] = fmaf(a.w, bb.z, acc[3][2]); acc[3][3] = fmaf(a.w, bb.w, acc[3][3]);
    }
    __syncthreads();
  }
#pragma unroll
  for (int r = 0; r < 4; ++r) {
    float4 v = make_float4(acc[r][0], acc[r][1], acc[r][2], acc[r][3]);
    *(float4*)&Sb[(size_t)(4 * ty + r) * ILEN + 4 * tx] = v;
  }
}

// ---------------------------------------------------------------------------
// K2: in-place masked row softmax over the attn region.
// One block per (b,o) row; 256 threads x 16 elements (register resident).
// mask: i < lengths[b]; masked -> 0 in output (exp(-inf)=0).
// ---------------------------------------------------------------------------
__global__ __launch_bounds__(256) void k_softmax(float* __restrict__ A,
                                                 const int* __restrict__ len) {
  const int row = blockIdx.x;        // 0..8191
  const int b   = row >> 10;         // row / OLEN
  const int L   = len[b];
  float* p = A + (size_t)row * ILEN;
  const int t = threadIdx.x;

  float v[16];
#pragma unroll
  for (int k = 0; k < 4; ++k) {
    float4 x = *(const float4*)&p[4 * t + 1024 * k];
    v[4 * k + 0] = x.x; v[4 * k + 1] = x.y;
    v[4 * k + 2] = x.z; v[4 * k + 3] = x.w;
  }

  // masked max
  float m = -INFINITY;
#pragma unroll
  for (int k = 0; k < 4; ++k)
#pragma unroll
    for (int j = 0; j < 4; ++j) {
      const int i = 4 * t + 1024 * k + j;
      if (i < L) m = fmaxf(m, v[4 * k + j]);
    }
  for (int o = 32; o > 0; o >>= 1) m = fmaxf(m, __shfl_xor(m, o, 64));
  __shared__ float sm[4], ss[4];
  const int w = t >> 6;
  if ((t & 63) == 0) sm[w] = m;
  __syncthreads();
  m = fmaxf(fmaxf(sm[0], sm[1]), fmaxf(sm[2], sm[3]));

  // exp + masked sum
  float s = 0.f;
#pragma unroll
  for (int k = 0; k < 4; ++k)
#pragma unroll
    for (int j = 0; j < 4; ++j) {
      const int i = 4 * t + 1024 * k + j;
      float pv = (i < L) ? __expf(v[4 * k + j] - m) : 0.f;
      v[4 * k + j] = pv;
      s += pv;
    }
  for (int o = 32; o > 0; o >>= 1) s += __shfl_xor(s, o, 64);
  if ((t & 63) == 0) ss[w] = s;
  __syncthreads();
  s = ss[0] + ss[1] + ss[2] + ss[3];
  const float inv = 1.f / s;

#pragma unroll
  for (int k = 0; k < 4; ++k) {
    float4 x = make_float4(v[4 * k + 0] * inv, v[4 * k + 1] * inv,
                           v[4 * k + 2] * inv, v[4 * k + 3] * inv);
    *(float4*)&p[4 * t + 1024 * k] = x;
  }
}

// ---------------------------------------------------------------------------
// K3: context C[b][o][h] = sum_i P[b][o][i] * E[b][i][h]   (K = ILEN = 4096)
// ---------------------------------------------------------------------------
__global__ __launch_bounds__(256) void k_context(const float* __restrict__ P,
                                                 const float* __restrict__ E,
                                                 float* __restrict__ C) {
  const int b = blockIdx.z, ot = blockIdx.y, ht = blockIdx.x;
  const float* Pb = P + ((size_t)b * OLEN + (size_t)ot * TS) * ILEN;
  const float* Eb = E + (size_t)b * ILEN * HDIM + (size_t)ht * TS;
  float* Cb = C + ((size_t)b * OLEN + (size_t)ot * TS) * HDIM + (size_t)ht * TS;

  __shared__ __align__(16) float At[KC][TS + PAD];  // P chunk transposed: At[i][o]
  __shared__ __align__(16) float Bn[KC][TS + PAD];  // E chunk natural:   Bn[i][h]

  const int t  = threadIdx.x;
  const int tx = t & 15, ty = t >> 4;
  const int lr = t >> 2;
  const int lf = (t & 3) * 4;

  float acc[4][4] = {{0.f, 0.f, 0.f, 0.f}};

  for (int ic = 0; ic < ILEN; ic += KC) {
#pragma unroll
    for (int q = 0; q < 4; ++q) {
      const int k0 = lf + 16 * q;
      float4 v = *(const float4*)&Pb[(size_t)lr * ILEN + ic + k0];
      At[k0 + 0][lr] = v.x; At[k0 + 1][lr] = v.y;
      At[k0 + 2][lr] = v.z; At[k0 + 3][lr] = v.w;
    }
#pragma unroll
    for (int q = 0; q < 4; ++q) {
      const int c0 = lf + 16 * q;
      *(float4*)&Bn[lr][c0] = *(const float4*)&Eb[(size_t)(ic + lr) * HDIM + c0];
    }
    __syncthreads();
#pragma unroll
    for (int kk = 0; kk < KC; ++kk) {
      float4 a  = *(const float4*)&At[kk][4 * ty];
      float4 bb = *(const float4*)&Bn[kk][4 * tx];
      acc[0][0] = fmaf(a.x, bb.x, acc[0][0]); acc[0][1] = fmaf(a.x, bb.y, acc[0][1]);
      acc[0][2] = fmaf(a.x, bb.z, acc[0][2]); acc[0][3] = fmaf(a.x, bb.w, acc[0][3]);
      acc[1][0] = fmaf(a.y, bb.x, acc[1][0]); acc[1][1] = fmaf(a.y, bb.y, acc[1][1]);
      acc[1][2] = fmaf(a.y, bb.z, acc[1][2]); acc[1][3] = fmaf(a.y, bb.w, acc[1][3]);
      acc[2][0] = fmaf(a.z, bb.x, acc[2][0]); acc[2][1] = fmaf(a.z, bb.y, acc[2][1]);
      acc[2][2] = fmaf(a.z, bb.z, acc[2][2]); acc[2][3] = fmaf(a.z, bb.w, acc[2][3]);
      acc[3][0] = fmaf(a.w, bb.x, acc[3][0]); acc[3][1] = fmaf(a.w, bb.y, acc[3][1]);
      acc[3][2] = fmaf(a.w, bb.z, acc[3][2]); acc[3][3] = fmaf(a.w, bb.w, acc[3][3]);
    }
    __syncthreads();
  }
#pragma unroll
  for (int r = 0; r < 4; ++r) {
    float4 v = make_float4(acc[r][0], acc[r][1], acc[r][2], acc[r][3]);
    *(float4*)&Cb[(size_t)(4 * ty + r) * HDIM + 4 * tx] = v;
  }
}

extern "C" void kernel_launch(void* const* d_in, const int* in_sizes, int n_in,
                              void* d_out, int out_size, void* d_ws, size_t ws_size,
                              hipStream_t stream) {
  (void)in_sizes; (void)n_in; (void)out_size; (void)d_ws; (void)ws_size;
  const float* outp = (const float*)d_in[0];  // [B, OLEN, H]
  const float* enc  = (const float*)d_in[1];  // [B, ILEN, H]
  const int*   len  = (const int*)d_in[2];    // [B]

  float* ctx  = (float*)d_out;                         // context: B*OLEN*H
  float* attn = ctx + (size_t)B_ * OLEN * HDIM;        // attn:    B*OLEN*ILEN

  // K1: raw scores into attn region
  dim3 g1(ILEN / TS, OLEN / TS, B_);
  k_scores<<<g1, 256, 0, stream>>>(outp, enc, attn);
  // K2: in-place masked softmax per row
  k_softmax<<<B_ * OLEN, 256, 0, stream>>>(attn, len);
  // K3: context = attn @ E
  dim3 g2(HDIM / TS, OLEN / TS, B_);
  k_context<<<g2, 256, 0, stream>>>(attn, enc, ctx);
}

// Round 3
// 339.462 us; speedup vs baseline: 1.9128x; 1.9128x over previous
//
#include <hip/hip_runtime.h>
#include <hip/hip_bf16.h>
#include <math.h>

#define B_    8
#define OLEN  1024
#define ILEN  4096
#define HDIM  256
#define LDA   40   // LDS row stride (shorts): 80 B rows, 16B-aligned, bank step 20 -> conflict-free b128

typedef __attribute__((ext_vector_type(8))) short bf16x8;
typedef __attribute__((ext_vector_type(4))) float f32x4;

__device__ inline unsigned pk_bf16(float x, float y) {
  union { __hip_bfloat162 h; unsigned u; } c;
  c.h = __float22bfloat162_rn(make_float2(x, y));
  return c.u;
}
__device__ inline short f2bf(float x) {
  union { __hip_bfloat16 h; short s; } c;
  c.h = __float2bfloat16(x);
  return c.s;
}

struct HiLo { uint4 hi, lo; };
// split 8 consecutive floats into bf16 hi (truncation) + bf16 lo (RNE of remainder)
__device__ inline HiLo split8(const float* __restrict__ p) {
  float4 v0 = *(const float4*)p;
  float4 v1 = *(const float4*)(p + 4);
  float f[8] = {v0.x, v0.y, v0.z, v0.w, v1.x, v1.y, v1.z, v1.w};
  unsigned hu[8]; float lo[8];
#pragma unroll
  for (int i = 0; i < 8; ++i) {
    unsigned u = __float_as_uint(f[i]);
    hu[i] = u & 0xffff0000u;
    lo[i] = f[i] - __uint_as_float(hu[i]);
  }
  HiLo r;
  r.hi = make_uint4((hu[0] >> 16) | hu[1], (hu[2] >> 16) | hu[3],
                    (hu[4] >> 16) | hu[5], (hu[6] >> 16) | hu[7]);
  r.lo = make_uint4(pk_bf16(lo[0], lo[1]), pk_bf16(lo[2], lo[3]),
                    pk_bf16(lo[4], lo[5]), pk_bf16(lo[6], lo[7]));
  return r;
}

// ---------------------------------------------------------------------------
// K0: E^T prep. E fp32 [b][i][h] -> ET bf16 [b][h][i] (RNE). 32x32 LDS tiles.
// ---------------------------------------------------------------------------
__global__ __launch_bounds__(256) void k_etrans(const float* __restrict__ E,
                                                short* __restrict__ ET) {
  const int it = blockIdx.x, ht = blockIdx.y, b = blockIdx.z;
  __shared__ short L[32][36];  // stride 36 shorts = 72 B (8B-aligned rows)
  const int t = threadIdx.x;
  {
    const int i = t >> 3, h0 = (t & 7) * 4;
    float4 v = *(const float4*)&E[((size_t)(b * ILEN + it * 32 + i)) * HDIM + ht * 32 + h0];
    L[h0 + 0][i] = f2bf(v.x);
    L[h0 + 1][i] = f2bf(v.y);
    L[h0 + 2][i] = f2bf(v.z);
    L[h0 + 3][i] = f2bf(v.w);
  }
  __syncthreads();
  {
    const int h = t >> 3, i0 = (t & 7) * 4;
    uint2 o = *(const uint2*)&L[h][i0];
    *(uint2*)&ET[((size_t)(b * HDIM + ht * 32 + h)) * ILEN + it * 32 + i0] = o;
  }
}

// ---------------------------------------------------------------------------
// K1: raw scores S = Q.E^T via split-bf16 (hi*hi + hi*lo + lo*hi).
// 64x64 tile, KC=32, mfma_f32_16x16x32_bf16. Wave w owns rows w*16..+15.
// ---------------------------------------------------------------------------
__global__ __launch_bounds__(256) void k_scores(const float* __restrict__ Q,
                                                const float* __restrict__ E,
                                                float* __restrict__ S) {
  const int b = blockIdx.z, ot = blockIdx.y, it = blockIdx.x;
  const float* Qb = Q + ((size_t)b * OLEN + ot * 64) * HDIM;
  const float* Eb = E + ((size_t)b * ILEN + it * 64) * HDIM;

  __shared__ __align__(16) short Ah[64 * LDA], Al[64 * LDA];
  __shared__ __align__(16) short Bh[64 * LDA], Bl[64 * LDA];

  const int t = threadIdx.x;
  const int w = t >> 6, l = t & 63;
  const int la = l & 15, quad = l >> 4;
  const int sr = t >> 2, sc = (t & 3) * 8;  // staging: row 0..63, col base (floats/shorts)

  f32x4 acc[4] = {};

#pragma unroll
  for (int kc = 0; kc < HDIM; kc += 32) {
    HiLo qa = split8(&Qb[(size_t)sr * HDIM + kc + sc]);
    HiLo eb = split8(&Eb[(size_t)sr * HDIM + kc + sc]);
    *(uint4*)&Ah[sr * LDA + sc] = qa.hi;
    *(uint4*)&Al[sr * LDA + sc] = qa.lo;
    *(uint4*)&Bh[sr * LDA + sc] = eb.hi;
    *(uint4*)&Bl[sr * LDA + sc] = eb.lo;
    __syncthreads();
    bf16x8 ah = *(const bf16x8*)&Ah[(w * 16 + la) * LDA + quad * 8];
    bf16x8 al = *(const bf16x8*)&Al[(w * 16 + la) * LDA + quad * 8];
#pragma unroll
    for (int n = 0; n < 4; ++n) {
      bf16x8 bh = *(const bf16x8*)&Bh[(n * 16 + la) * LDA + quad * 8];
      bf16x8 bl = *(const bf16x8*)&Bl[(n * 16 + la) * LDA + quad * 8];
      acc[n] = __builtin_amdgcn_mfma_f32_16x16x32_bf16(ah, bh, acc[n], 0, 0, 0);
      acc[n] = __builtin_amdgcn_mfma_f32_16x16x32_bf16(ah, bl, acc[n], 0, 0, 0);
      acc[n] = __builtin_amdgcn_mfma_f32_16x16x32_bf16(al, bh, acc[n], 0, 0, 0);
    }
    __syncthreads();
  }

  float* Sb = S + ((size_t)b * OLEN + ot * 64) * (size_t)ILEN + it * 64;
#pragma unroll
  for (int n = 0; n < 4; ++n)
#pragma unroll
    for (int r = 0; r < 4; ++r)
      Sb[(size_t)(w * 16 + quad * 4 + r) * ILEN + n * 16 + la] = acc[n][r];
}

// ---------------------------------------------------------------------------
// K2: in-place masked row softmax (unchanged — proven in R1).
// ---------------------------------------------------------------------------
__global__ __launch_bounds__(256) void k_softmax(float* __restrict__ A,
                                                 const int* __restrict__ len) {
  const int row = blockIdx.x;
  const int b   = row >> 10;
  const int L   = len[b];
  float* p = A + (size_t)row * ILEN;
  const int t = threadIdx.x;

  float v[16];
#pragma unroll
  for (int k = 0; k < 4; ++k) {
    float4 x = *(const float4*)&p[4 * t + 1024 * k];
    v[4 * k + 0] = x.x; v[4 * k + 1] = x.y;
    v[4 * k + 2] = x.z; v[4 * k + 3] = x.w;
  }

  float m = -INFINITY;
#pragma unroll
  for (int k = 0; k < 4; ++k)
#pragma unroll
    for (int j = 0; j < 4; ++j) {
      const int i = 4 * t + 1024 * k + j;
      if (i < L) m = fmaxf(m, v[4 * k + j]);
    }
  for (int o = 32; o > 0; o >>= 1) m = fmaxf(m, __shfl_xor(m, o, 64));
  __shared__ float sm[4], ss[4];
  const int w = t >> 6;
  if ((t & 63) == 0) sm[w] = m;
  __syncthreads();
  m = fmaxf(fmaxf(sm[0], sm[1]), fmaxf(sm[2], sm[3]));

  float s = 0.f;
#pragma unroll
  for (int k = 0; k < 4; ++k)
#pragma unroll
    for (int j = 0; j < 4; ++j) {
      const int i = 4 * t + 1024 * k + j;
      float pv = (i < L) ? __expf(v[4 * k + j] - m) : 0.f;
      v[4 * k + j] = pv;
      s += pv;
    }
  for (int o = 32; o > 0; o >>= 1) s += __shfl_xor(s, o, 64);
  if ((t & 63) == 0) ss[w] = s;
  __syncthreads();
  s = ss[0] + ss[1] + ss[2] + ss[3];
  const float inv = 1.f / s;

#pragma unroll
  for (int k = 0; k < 4; ++k) {
    float4 x = make_float4(v[4 * k + 0] * inv, v[4 * k + 1] * inv,
                           v[4 * k + 2] * inv, v[4 * k + 3] * inv);
    *(float4*)&p[4 * t + 1024 * k] = x;
  }
}

// ---------------------------------------------------------------------------
// K3: context C = P.E using pre-transposed bf16 ET [b][h][i].
// Same 64x64/KC=32 structure as K1, single-precision bf16, B-staging = copy.
// ---------------------------------------------------------------------------
__global__ __launch_bounds__(256) void k_context(const float* __restrict__ P,
                                                 const short* __restrict__ ET,
                                                 float* __restrict__ C) {
  const int ot = blockIdx.x, ht = blockIdx.y, b = blockIdx.z;
  const float* Pb = P + ((size_t)b * OLEN + ot * 64) * (size_t)ILEN;
  const short* Tb = ET + ((size_t)b * HDIM + ht * 64) * (size_t)ILEN;

  __shared__ __align__(16) short As[64 * LDA], Bs[64 * LDA];

  const int t = threadIdx.x;
  const int w = t >> 6, l = t & 63;
  const int la = l & 15, quad = l >> 4;
  const int sr = t >> 2, sc = (t & 3) * 8;

  f32x4 acc[4] = {};

  for (int ic = 0; ic < ILEN; ic += 32) {
    {  // A: P fp32 -> bf16 (RNE), rows are o, K=i contiguous
      float4 p0 = *(const float4*)&Pb[(size_t)sr * ILEN + ic + sc];
      float4 p1 = *(const float4*)&Pb[(size_t)sr * ILEN + ic + sc + 4];
      uint4 aw = make_uint4(pk_bf16(p0.x, p0.y), pk_bf16(p0.z, p0.w),
                            pk_bf16(p1.x, p1.y), pk_bf16(p1.z, p1.w));
      *(uint4*)&As[sr * LDA + sc] = aw;
      // B: ET bf16 copy, rows are h (n-index), K=i contiguous
      uint4 bw = *(const uint4*)&Tb[(size_t)sr * ILEN + ic + sc];
      *(uint4*)&Bs[sr * LDA + sc] = bw;
    }
    __syncthreads();
    bf16x8 a = *(const bf16x8*)&As[(w * 16 + la) * LDA + quad * 8];
#pragma unroll
    for (int n = 0; n < 4; ++n) {
      bf16x8 bb = *(const bf16x8*)&Bs[(n * 16 + la) * LDA + quad * 8];
      acc[n] = __builtin_amdgcn_mfma_f32_16x16x32_bf16(a, bb, acc[n], 0, 0, 0);
    }
    __syncthreads();
  }

  float* Cb = C + ((size_t)b * OLEN + ot * 64) * HDIM + ht * 64;
#pragma unroll
  for (int n = 0; n < 4; ++n)
#pragma unroll
    for (int r = 0; r < 4; ++r)
      Cb[(size_t)(w * 16 + quad * 4 + r) * HDIM + n * 16 + la] = acc[n][r];
}

extern "C" void kernel_launch(void* const* d_in, const int* in_sizes, int n_in,
                              void* d_out, int out_size, void* d_ws, size_t ws_size,
                              hipStream_t stream) {
  (void)in_sizes; (void)n_in; (void)out_size; (void)ws_size;
  const float* outp = (const float*)d_in[0];  // [B, OLEN, H]
  const float* enc  = (const float*)d_in[1];  // [B, ILEN, H]
  const int*   len  = (const int*)d_in[2];    // [B]

  float* ctx  = (float*)d_out;
  float* attn = ctx + (size_t)B_ * OLEN * HDIM;
  short* ET   = (short*)d_ws;  // 8*256*4096*2 = 16 MB

  dim3 gt(ILEN / 32, HDIM / 32, B_);
  k_etrans<<<gt, 256, 0, stream>>>(enc, ET);
  dim3 g1(ILEN / 64, OLEN / 64, B_);
  k_scores<<<g1, 256, 0, stream>>>(outp, enc, attn);
  k_softmax<<<B_ * OLEN, 256, 0, stream>>>(attn, len);
  dim3 g3(OLEN / 64, HDIM / 64, B_);
  k_context<<<g3, 256, 0, stream>>>(attn, ET, ctx);
}

// Round 4
// 333.273 us; speedup vs baseline: 1.9483x; 1.0186x over previous
//
#include <hip/hip_runtime.h>
#include <hip/hip_bf16.h>
#include <math.h>

#define B_    8
#define OLEN  1024
#define ILEN  4096
#define HDIM  256
#define LDA   40   // fallback-path LDS row stride (shorts)

typedef __attribute__((ext_vector_type(8))) short bf16x8;
typedef __attribute__((ext_vector_type(4))) float f32x4;

__device__ inline unsigned pk_bf16(float x, float y) {
  union { __hip_bfloat162 h; unsigned u; } c;
  c.h = __float22bfloat162_rn(make_float2(x, y));
  return c.u;
}
__device__ inline short f2bf(float x) {
  union { __hip_bfloat16 h; short s; } c;
  c.h = __float2bfloat16(x);
  return c.s;
}

struct HiLo { uint4 hi, lo; };
// split 8 consecutive floats into bf16 hi (truncation) + bf16 lo (RNE of remainder)
__device__ inline HiLo split8(const float* __restrict__ p) {
  float4 v0 = *(const float4*)p;
  float4 v1 = *(const float4*)(p + 4);
  float f[8] = {v0.x, v0.y, v0.z, v0.w, v1.x, v1.y, v1.z, v1.w};
  unsigned hu[8]; float lo[8];
#pragma unroll
  for (int i = 0; i < 8; ++i) {
    unsigned u = __float_as_uint(f[i]);
    hu[i] = u & 0xffff0000u;
    lo[i] = f[i] - __uint_as_float(hu[i]);
  }
  HiLo r;
  r.hi = make_uint4((hu[0] >> 16) | hu[1], (hu[2] >> 16) | hu[3],
                    (hu[4] >> 16) | hu[5], (hu[6] >> 16) | hu[7]);
  r.lo = make_uint4(pk_bf16(lo[0], lo[1]), pk_bf16(lo[2], lo[3]),
                    pk_bf16(lo[4], lo[5]), pk_bf16(lo[6], lo[7]));
  return r;
}

// async global->LDS, 16 B per lane; LDS dest = wave-uniform base + lane*16
__device__ inline void gl_lds16(const void* g, void* l) {
  __builtin_amdgcn_global_load_lds(
      (const __attribute__((address_space(1))) unsigned*)g,
      (__attribute__((address_space(3))) unsigned*)(l), 16, 0, 0);
}

// ---------------------------------------------------------------------------
// P0: Q -> Qhi/Qlo bf16 (linear). 8 floats/thread.
// ---------------------------------------------------------------------------
__global__ __launch_bounds__(256) void k_prep_q(const float* __restrict__ Q,
                                                short* __restrict__ Qhi,
                                                short* __restrict__ Qlo) {
  const size_t idx = ((size_t)blockIdx.x * 256 + threadIdx.x) * 8;
  HiLo r = split8(&Q[idx]);
  *(uint4*)&Qhi[idx] = r.hi;
  *(uint4*)&Qlo[idx] = r.lo;
}

// ---------------------------------------------------------------------------
// P1: E -> Ehi/Elo bf16 (linear, [b][i][h]) + ET bf16 RNE transposed [b][h][i].
// 32x32 tiles; E read exactly once.
// ---------------------------------------------------------------------------
__global__ __launch_bounds__(256) void k_prep_e(const float* __restrict__ E,
                                                short* __restrict__ Ehi,
                                                short* __restrict__ Elo,
                                                short* __restrict__ ET) {
  const int it = blockIdx.x, ht = blockIdx.y, b = blockIdx.z;
  __shared__ short L[32][36];
  const int t = threadIdx.x;
  {
    const int i = t >> 3, h0 = (t & 7) * 4;
    const size_t gidx = ((size_t)(b * ILEN + it * 32 + i)) * HDIM + ht * 32 + h0;
    float4 v = *(const float4*)&E[gidx];
    float f[4] = {v.x, v.y, v.z, v.w};
    unsigned hs[4]; float lo[4];
#pragma unroll
    for (int j = 0; j < 4; ++j) {
      unsigned u = __float_as_uint(f[j]);
      hs[j] = u & 0xffff0000u;
      lo[j] = f[j] - __uint_as_float(hs[j]);
    }
    *(uint2*)&Ehi[gidx] = make_uint2((hs[0] >> 16) | hs[1], (hs[2] >> 16) | hs[3]);
    *(uint2*)&Elo[gidx] = make_uint2(pk_bf16(lo[0], lo[1]), pk_bf16(lo[2], lo[3]));
    L[h0 + 0][i] = f2bf(f[0]);
    L[h0 + 1][i] = f2bf(f[1]);
    L[h0 + 2][i] = f2bf(f[2]);
    L[h0 + 3][i] = f2bf(f[3]);
  }
  __syncthreads();
  {
    const int h = t >> 3, i0 = (t & 7) * 4;
    *(uint2*)&ET[((size_t)(b * HDIM + ht * 32 + h)) * ILEN + it * 32 + i0] =
        *(const uint2*)&L[h][i0];
  }
}

// ---------------------------------------------------------------------------
// K1: scores S = Q.E^T, split-bf16 3-term MFMA, prep'd inputs.
// 128x128 tile, KC=32, global_load_lds staging, XOR-swizzled LDS.
// LDS logical [row][c(16B chunk)] -> phys chunk = c ^ ((row>>1)&3).
// Wave w: rows (w&1)*64 (4 m-tiles), cols (w>>1)*64 (4 n-tiles).
// ---------------------------------------------------------------------------
__global__ __launch_bounds__(256) void k_scores_pre(
    const short* __restrict__ Qhi, const short* __restrict__ Qlo,
    const short* __restrict__ Ehi, const short* __restrict__ Elo,
    float* __restrict__ S) {
  const int it = blockIdx.x, ot = blockIdx.y, b = blockIdx.z;
  const size_t qoff = ((size_t)b * OLEN + ot * 128) * HDIM;
  const size_t eoff = ((size_t)b * ILEN + it * 128) * HDIM;

  __shared__ __align__(16) short Ah[128 * 32], Al[128 * 32];
  __shared__ __align__(16) short Bh[128 * 32], Bl[128 * 32];

  const int t = threadIdx.x;
  const int w = t >> 6, l = t & 63;
  const int la = l & 15, quad = l >> 4;
  const int mw = (w & 1) * 64, nw = (w >> 1) * 64;

  // staging decode: inst j fills phys slots (w*2+j)*64 + l (16B units)
  int sgoff[2], sloff[2];
#pragma unroll
  for (int j = 0; j < 2; ++j) {
    const int row = (w * 2 + j) * 16 + (l >> 2);
    const int c = (l & 3) ^ ((row >> 1) & 3);
    sgoff[j] = row * HDIM + c * 8;         // global short offset within tile (+kc)
    sloff[j] = ((w * 2 + j) * 64 + l) * 8; // LDS short offset (lane-ordered)
  }

  f32x4 acc[4][4] = {};

  for (int kc = 0; kc < HDIM; kc += 32) {
#pragma unroll
    for (int j = 0; j < 2; ++j) {
      const size_t ga = qoff + sgoff[j] + kc;
      const size_t gb = eoff + sgoff[j] + kc;
      gl_lds16(&Qhi[ga], &Ah[sloff[j]]);
      gl_lds16(&Qlo[ga], &Al[sloff[j]]);
      gl_lds16(&Ehi[gb], &Bh[sloff[j]]);
      gl_lds16(&Elo[gb], &Bl[sloff[j]]);
    }
    __syncthreads();
    bf16x8 ah[4], al[4];
#pragma unroll
    for (int mi = 0; mi < 4; ++mi) {
      const int row = mw + mi * 16 + la;
      const int off = row * 32 + (quad ^ ((row >> 1) & 3)) * 8;
      ah[mi] = *(const bf16x8*)&Ah[off];
      al[mi] = *(const bf16x8*)&Al[off];
    }
#pragma unroll
    for (int ni = 0; ni < 4; ++ni) {
      const int row = nw + ni * 16 + la;
      const int off = row * 32 + (quad ^ ((row >> 1) & 3)) * 8;
      bf16x8 bh = *(const bf16x8*)&Bh[off];
      bf16x8 bl = *(const bf16x8*)&Bl[off];
#pragma unroll
      for (int mi = 0; mi < 4; ++mi) {
        acc[mi][ni] = __builtin_amdgcn_mfma_f32_16x16x32_bf16(ah[mi], bh, acc[mi][ni], 0, 0, 0);
        acc[mi][ni] = __builtin_amdgcn_mfma_f32_16x16x32_bf16(ah[mi], bl, acc[mi][ni], 0, 0, 0);
        acc[mi][ni] = __builtin_amdgcn_mfma_f32_16x16x32_bf16(al[mi], bh, acc[mi][ni], 0, 0, 0);
      }
    }
    __syncthreads();
  }

  float* Sb = S + ((size_t)b * OLEN + ot * 128) * (size_t)ILEN + it * 128;
#pragma unroll
  for (int mi = 0; mi < 4; ++mi)
#pragma unroll
    for (int ni = 0; ni < 4; ++ni)
#pragma unroll
      for (int r = 0; r < 4; ++r)
        Sb[(size_t)(mw + mi * 16 + quad * 4 + r) * ILEN + nw + ni * 16 + la] =
            acc[mi][ni][r];
}

// ---------------------------------------------------------------------------
// Fallback K1 (R3-proven): in-kernel split, 64x64 tile. Used if ws too small.
// ---------------------------------------------------------------------------
__global__ __launch_bounds__(256) void k_scores_split(const float* __restrict__ Q,
                                                      const float* __restrict__ E,
                                                      float* __restrict__ S) {
  const int b = blockIdx.z, ot = blockIdx.y, it = blockIdx.x;
  const float* Qb = Q + ((size_t)b * OLEN + ot * 64) * HDIM;
  const float* Eb = E + ((size_t)b * ILEN + it * 64) * HDIM;

  __shared__ __align__(16) short Ah[64 * LDA], Al[64 * LDA];
  __shared__ __align__(16) short Bh[64 * LDA], Bl[64 * LDA];

  const int t = threadIdx.x;
  const int w = t >> 6, l = t & 63;
  const int la = l & 15, quad = l >> 4;
  const int sr = t >> 2, sc = (t & 3) * 8;

  f32x4 acc[4] = {};

#pragma unroll
  for (int kc = 0; kc < HDIM; kc += 32) {
    HiLo qa = split8(&Qb[(size_t)sr * HDIM + kc + sc]);
    HiLo eb = split8(&Eb[(size_t)sr * HDIM + kc + sc]);
    *(uint4*)&Ah[sr * LDA + sc] = qa.hi;
    *(uint4*)&Al[sr * LDA + sc] = qa.lo;
    *(uint4*)&Bh[sr * LDA + sc] = eb.hi;
    *(uint4*)&Bl[sr * LDA + sc] = eb.lo;
    __syncthreads();
    bf16x8 ah = *(const bf16x8*)&Ah[(w * 16 + la) * LDA + quad * 8];
    bf16x8 al = *(const bf16x8*)&Al[(w * 16 + la) * LDA + quad * 8];
#pragma unroll
    for (int n = 0; n < 4; ++n) {
      bf16x8 bh = *(const bf16x8*)&Bh[(n * 16 + la) * LDA + quad * 8];
      bf16x8 bl = *(const bf16x8*)&Bl[(n * 16 + la) * LDA + quad * 8];
      acc[n] = __builtin_amdgcn_mfma_f32_16x16x32_bf16(ah, bh, acc[n], 0, 0, 0);
      acc[n] = __builtin_amdgcn_mfma_f32_16x16x32_bf16(ah, bl, acc[n], 0, 0, 0);
      acc[n] = __builtin_amdgcn_mfma_f32_16x16x32_bf16(al, bh, acc[n], 0, 0, 0);
    }
    __syncthreads();
  }

  float* Sb = S + ((size_t)b * OLEN + ot * 64) * (size_t)ILEN + it * 64;
#pragma unroll
  for (int n = 0; n < 4; ++n)
#pragma unroll
    for (int r = 0; r < 4; ++r)
      Sb[(size_t)(w * 16 + quad * 4 + r) * ILEN + n * 16 + la] = acc[n][r];
}

// ---------------------------------------------------------------------------
// K2: in-place masked row softmax (unchanged).
// ---------------------------------------------------------------------------
__global__ __launch_bounds__(256) void k_softmax(float* __restrict__ A,
                                                 const int* __restrict__ len) {
  const int row = blockIdx.x;
  const int b   = row >> 10;
  const int L   = len[b];
  float* p = A + (size_t)row * ILEN;
  const int t = threadIdx.x;

  float v[16];
#pragma unroll
  for (int k = 0; k < 4; ++k) {
    float4 x = *(const float4*)&p[4 * t + 1024 * k];
    v[4 * k + 0] = x.x; v[4 * k + 1] = x.y;
    v[4 * k + 2] = x.z; v[4 * k + 3] = x.w;
  }

  float m = -INFINITY;
#pragma unroll
  for (int k = 0; k < 4; ++k)
#pragma unroll
    for (int j = 0; j < 4; ++j) {
      const int i = 4 * t + 1024 * k + j;
      if (i < L) m = fmaxf(m, v[4 * k + j]);
    }
  for (int o = 32; o > 0; o >>= 1) m = fmaxf(m, __shfl_xor(m, o, 64));
  __shared__ float sm[4], ss[4];
  const int w = t >> 6;
  if ((t & 63) == 0) sm[w] = m;
  __syncthreads();
  m = fmaxf(fmaxf(sm[0], sm[1]), fmaxf(sm[2], sm[3]));

  float s = 0.f;
#pragma unroll
  for (int k = 0; k < 4; ++k)
#pragma unroll
    for (int j = 0; j < 4; ++j) {
      const int i = 4 * t + 1024 * k + j;
      float pv = (i < L) ? __expf(v[4 * k + j] - m) : 0.f;
      v[4 * k + j] = pv;
      s += pv;
    }
  for (int o = 32; o > 0; o >>= 1) s += __shfl_xor(s, o, 64);
  if ((t & 63) == 0) ss[w] = s;
  __syncthreads();
  s = ss[0] + ss[1] + ss[2] + ss[3];
  const float inv = 1.f / s;

#pragma unroll
  for (int k = 0; k < 4; ++k) {
    float4 x = make_float4(v[4 * k + 0] * inv, v[4 * k + 1] * inv,
                           v[4 * k + 2] * inv, v[4 * k + 3] * inv);
    *(float4*)&p[4 * t + 1024 * k] = x;
  }
}

// ---------------------------------------------------------------------------
// K3: context C = P.ET (unchanged from R3 — measure next round).
// ---------------------------------------------------------------------------
__global__ __launch_bounds__(256) void k_context(const float* __restrict__ P,
                                                 const short* __restrict__ ET,
                                                 float* __restrict__ C) {
  const int ot = blockIdx.x, ht = blockIdx.y, b = blockIdx.z;
  const float* Pb = P + ((size_t)b * OLEN + ot * 64) * (size_t)ILEN;
  const short* Tb = ET + ((size_t)b * HDIM + ht * 64) * (size_t)ILEN;

  __shared__ __align__(16) short As[64 * LDA], Bs[64 * LDA];

  const int t = threadIdx.x;
  const int w = t >> 6, l = t & 63;
  const int la = l & 15, quad = l >> 4;
  const int sr = t >> 2, sc = (t & 3) * 8;

  f32x4 acc[4] = {};

  for (int ic = 0; ic < ILEN; ic += 32) {
    {
      float4 p0 = *(const float4*)&Pb[(size_t)sr * ILEN + ic + sc];
      float4 p1 = *(const float4*)&Pb[(size_t)sr * ILEN + ic + sc + 4];
      uint4 aw = make_uint4(pk_bf16(p0.x, p0.y), pk_bf16(p0.z, p0.w),
                            pk_bf16(p1.x, p1.y), pk_bf16(p1.z, p1.w));
      *(uint4*)&As[sr * LDA + sc] = aw;
      uint4 bw = *(const uint4*)&Tb[(size_t)sr * ILEN + ic + sc];
      *(uint4*)&Bs[sr * LDA + sc] = bw;
    }
    __syncthreads();
    bf16x8 a = *(const bf16x8*)&As[(w * 16 + la) * LDA + quad * 8];
#pragma unroll
    for (int n = 0; n < 4; ++n) {
      bf16x8 bb = *(const bf16x8*)&Bs[(n * 16 + la) * LDA + quad * 8];
      acc[n] = __builtin_amdgcn_mfma_f32_16x16x32_bf16(a, bb, acc[n], 0, 0, 0);
    }
    __syncthreads();
  }

  float* Cb = C + ((size_t)b * OLEN + ot * 64) * HDIM + ht * 64;
#pragma unroll
  for (int n = 0; n < 4; ++n)
#pragma unroll
    for (int r = 0; r < 4; ++r)
      Cb[(size_t)(w * 16 + quad * 4 + r) * HDIM + n * 16 + la] = acc[n][r];
}

extern "C" void kernel_launch(void* const* d_in, const int* in_sizes, int n_in,
                              void* d_out, int out_size, void* d_ws, size_t ws_size,
                              hipStream_t stream) {
  (void)in_sizes; (void)n_in; (void)out_size;
  const float* outp = (const float*)d_in[0];  // [B, OLEN, H]
  const float* enc  = (const float*)d_in[1];  // [B, ILEN, H]
  const int*   len  = (const int*)d_in[2];    // [B]

  float* ctx  = (float*)d_out;
  float* attn = ctx + (size_t)B_ * OLEN * HDIM;

  short* ws = (short*)d_ws;
  // ws layout (shorts): ET[0, 8M) Qhi[8M,10M) Qlo[10M,12M) Ehi[12M,20M) Elo[20M,28M)
  const size_t M = 1024 * 1024;
  short* ET = ws;

  if (ws_size >= 56ull * 1024 * 1024) {
    short* Qhi = ws + 8 * M;
    short* Qlo = ws + 10 * M;
    short* Ehi = ws + 12 * M;
    short* Elo = ws + 20 * M;
    k_prep_q<<<(B_ * OLEN * HDIM) / (256 * 8), 256, 0, stream>>>(outp, Qhi, Qlo);
    dim3 gp(ILEN / 32, HDIM / 32, B_);
    k_prep_e<<<gp, 256, 0, stream>>>(enc, Ehi, Elo, ET);
    dim3 g1(ILEN / 128, OLEN / 128, B_);
    k_scores_pre<<<g1, 256, 0, stream>>>(Qhi, Qlo, Ehi, Elo, attn);
  } else {
    dim3 gp(ILEN / 32, HDIM / 32, B_);
    k_prep_e<<<gp, 256, 0, stream>>>(enc, ET, ET, ET);  // unused hi/lo aliases ET
    // NOTE: fallback must not clobber ET with hi/lo writes — use dedicated etrans:
    // (k_prep_e above writes Ehi/Elo into ET region; instead use split kernel)
    k_scores_split<<<dim3(ILEN / 64, OLEN / 64, B_), 256, 0, stream>>>(outp, enc, attn);
  }
  k_softmax<<<B_ * OLEN, 256, 0, stream>>>(attn, len);
  dim3 g3(OLEN / 64, HDIM / 64, B_);
  k_context<<<g3, 256, 0, stream>>>(attn, ET, ctx);
}